// Round 6
// baseline (447.006 us; speedup 1.0000x reference)
//
#include <hip/hip_runtime.h>
#include <stdint.h>

#define N_NODES 500000
#define K_NB 16
#define F_IN 7
#define F_HID 40
#define F_OUT 3
#define NODE_FLOATS (K_NB * F_IN)   // 112 floats = 28 float4 per node
#define NPW 16                      // nodes per wave-tile
#define WPB 4                       // waves per block
#define NPB (NPW * WPB)             // 64 nodes per block
#define NBLK ((N_NODES + NPB - 1) / NPB)  // 7813
#define REP 3                       // grid replication: DIAGNOSTIC (see below)

typedef __attribute__((address_space(3))) void lds_void_t;
typedef __attribute__((address_space(1))) const void glb_void_t;

// ROUND 6 = ROUND 3 KERNEL x3 GRID REPLICAS (rocprof visibility probe).
// R5 self-differencing: T_kernel(R3) ~= 71.6us vs 36us HBM floor, but the
// kernel has NEVER appeared in rocprof top-5 (harness fills at ~133us own all
// slots), so VALUBusy/LDS-conflict/occupancy for it are unknown and R4's
// neutral result is unexplainable. 3 replicas (blockIdx.x % NBLK) compute and
// write IDENTICAL values (benign races, idempotent, graph-legal): dispatch
// ~215us -> ranks #1 -> real counters. Next round drops REP and acts on them.
__global__ __launch_bounds__(256) void aggre_kernel(
    const float* __restrict__ mailbox,
    const float* __restrict__ W1,
    const float* __restrict__ b1,
    const float* __restrict__ W2,
    const float* __restrict__ b2,
    float* __restrict__ out)
{
    __shared__ float4 w1lds[F_HID * 2];  // [h*2+0]=W1[0..3][h]; [h*2+1]={W1[4..6][h], b1[h]}
    __shared__ float4 w2lds[F_HID];      // [h]={W2[h][0..2], 0}
    __shared__ __align__(16) float tile[WPB][NPW * NODE_FLOATS];  // 4 x 7168 B

    const int t = threadIdx.x;
    if (t < F_HID * 2) {
        const int h = t >> 1;
        float4 v;
        if ((t & 1) == 0) {
            v.x = W1[0 * F_HID + h]; v.y = W1[1 * F_HID + h];
            v.z = W1[2 * F_HID + h]; v.w = W1[3 * F_HID + h];
        } else {
            v.x = W1[4 * F_HID + h]; v.y = W1[5 * F_HID + h];
            v.z = W1[6 * F_HID + h]; v.w = b1[h];
        }
        w1lds[t] = v;
    } else if (t < F_HID * 3) {
        const int h = t - F_HID * 2;
        float4 v;
        v.x = W2[h * F_OUT + 0];
        v.y = W2[h * F_OUT + 1];
        v.z = W2[h * F_OUT + 2];
        v.w = 0.0f;
        w2lds[h] = v;
    }
    __syncthreads();

    const unsigned bid = (unsigned)blockIdx.x % (unsigned)NBLK;  // 3 replicas -> same work
    const int wave = t >> 6;
    const int lane = t & 63;
    const long tile0 = (long)bid * NPB + (long)wave * NPW;
    if (tile0 >= N_NODES) return;  // wave-uniform; after the only barrier

    // ---- stage 16 nodes, coalesced, direct-to-LDS ----
    const float* gsrc = mailbox + (size_t)tile0 * NODE_FLOATS;
    #pragma unroll
    for (int j = 0; j < 7; ++j) {
        const float* g = gsrc + (size_t)(j * 64 + lane) * 4;
        __builtin_amdgcn_global_load_lds(
            (glb_void_t*)g,
            (lds_void_t*)&tile[wave][j * 256],
            16, 0, 0);
    }
    __builtin_amdgcn_s_waitcnt(0x0f70);  // vmcnt(0)

    // ---- per-quad compute: lane r of node nloc handles k = 4r..4r+3 ----
    const int nloc = lane >> 2;
    const int r = lane & 3;
    const float* mp = &tile[wave][nloc * NODE_FLOATS + r * 28];
    float m[28];
    #pragma unroll
    for (int i = 0; i < 7; ++i) {
        const float4 v = ((const float4*)mp)[i];
        m[4 * i + 0] = v.x; m[4 * i + 1] = v.y;
        m[4 * i + 2] = v.z; m[4 * i + 3] = v.w;
    }

    float a0 = 0.0f, a1 = 0.0f, a2 = 0.0f;
    #pragma unroll 2
    for (int h = 0; h < F_HID; ++h) {
        const float4 wa = w1lds[2 * h + 0];   // broadcast ds_read
        const float4 wb = w1lds[2 * h + 1];   // wb.w = b1[h]
        float sh = 0.0f;
        #pragma unroll
        for (int kk = 0; kk < 4; ++kk) {
            const int o = kk * F_IN;
            float acc = wb.w;
            acc = fmaf(m[o + 0], wa.x, acc);
            acc = fmaf(m[o + 1], wa.y, acc);
            acc = fmaf(m[o + 2], wa.z, acc);
            acc = fmaf(m[o + 3], wa.w, acc);
            acc = fmaf(m[o + 4], wb.x, acc);
            acc = fmaf(m[o + 5], wb.y, acc);
            acc = fmaf(m[o + 6], wb.z, acc);
            sh += fmaxf(acc, 0.0f);
        }
        const float4 w2v = w2lds[h];
        a0 = fmaf(sh, w2v.x, a0);
        a1 = fmaf(sh, w2v.y, a1);
        a2 = fmaf(sh, w2v.z, a2);
    }

    // ---- reduce the 4 k-partials within each quad ----
    a0 += __shfl_xor(a0, 1); a0 += __shfl_xor(a0, 2);
    a1 += __shfl_xor(a1, 1); a1 += __shfl_xor(a1, 2);
    a2 += __shfl_xor(a2, 1); a2 += __shfl_xor(a2, 2);

    if (r < F_OUT) {
        const float val = (r == 0) ? a0 : ((r == 1) ? a1 : a2);
        out[(size_t)(tile0 + nloc) * F_OUT + r] =
            fmaf(val, 1.0f / (float)K_NB, b2[r]);
    }
}

extern "C" void kernel_launch(void* const* d_in, const int* in_sizes, int n_in,
                              void* d_out, int out_size, void* d_ws, size_t ws_size,
                              hipStream_t stream) {
    const float* mailbox = (const float*)d_in[0];
    const float* W1      = (const float*)d_in[1];
    const float* b1      = (const float*)d_in[2];
    const float* W2      = (const float*)d_in[3];
    const float* b2      = (const float*)d_in[4];
    float* out = (float*)d_out;

    aggre_kernel<<<NBLK * REP, 256, 0, stream>>>(mailbox, W1, b1, W2, b2, out);
}

// Round 7
// 317.932 us; speedup vs baseline: 1.4060x; 1.4060x over previous
//
#include <hip/hip_runtime.h>
#include <stdint.h>

#define N_NODES 500000
#define K_NB 16
#define F_IN 7
#define F_HID 40
#define F_OUT 3
#define NODE_FLOATS (K_NB * F_IN)   // 112 floats per node
#define NPW 16                      // nodes per wave-tile
#define WPB 4                       // waves per block
#define NPB (NPW * WPB)             // 64 nodes per block
#define NBLK ((N_NODES + NPB - 1) / NPB)  // 7813

typedef float v2f __attribute__((ext_vector_type(2)));

typedef __attribute__((address_space(3))) void lds_void_t;
typedef __attribute__((address_space(1))) const void glb_void_t;
typedef __attribute__((address_space(4))) const float kfloat;  // constant AS -> s_load

// R6 diagnosis: LDS pipe saturation. 120 broadcast ds_read_b128 weight reads
// + 7 tile reads = 127 x 12cyc = 1524 LDS-cyc/wave; 122 waves/CU -> 77.5us,
// matching the 80us/rep measured. Broadcast pays full data-return cost.
// Fix: weights leave the LDS pipe entirely -> SMEM (s_load) via addrspace(4)
// loads of a prep-packed table (wave-uniform address). Tile reads become 14
// ds_read2_b32 vertical k-pairs feeding v_pk_*_f32 packed math.
__global__ void prep_kernel(const float* __restrict__ W1,
                            const float* __restrict__ b1,
                            const float* __restrict__ W2,
                            float* __restrict__ ws)
{
    const int t = threadIdx.x;
    if (t < F_HID) {
        // wtab row h (8 floats, 32B): {W1[0][h]..W1[6][h], b1[h]}
        float* p = ws + t * 8;
        #pragma unroll
        for (int i = 0; i < F_IN; ++i) p[i] = W1[i * F_HID + t];
        p[7] = b1[t];
    } else if (t < 2 * F_HID) {
        // w2tab row h (4 floats): {W2[h][0..2], 0}
        const int h = t - F_HID;
        float* p = ws + F_HID * 8 + h * 4;
        p[0] = W2[h * F_OUT + 0];
        p[1] = W2[h * F_OUT + 1];
        p[2] = W2[h * F_OUT + 2];
        p[3] = 0.0f;
    }
}

__global__ __launch_bounds__(256) void aggre_kernel(
    const float* __restrict__ mailbox,
    const float* __restrict__ wtab,   // [40][8]: W1 rows + b1 (prep-packed)
    const float* __restrict__ w2tab,  // [40][4]: W2 rows
    const float* __restrict__ b2,
    float* __restrict__ out)
{
    __shared__ __align__(16) float tile[WPB][NPW * NODE_FLOATS];  // 4 x 7168 B (weights NOT in LDS)

    const int t = threadIdx.x;
    const int wave = t >> 6;
    const int lane = t & 63;
    const long tile0 = (long)blockIdx.x * NPB + (long)wave * NPW;
    if (tile0 >= N_NODES) return;   // wave-uniform; no barriers in this kernel

    // ---- stage 16 nodes (7168 B), coalesced, direct-to-LDS (proven R3 path) ----
    const float* gsrc = mailbox + (size_t)tile0 * NODE_FLOATS;
    #pragma unroll
    for (int j = 0; j < 7; ++j) {
        const float* g = gsrc + (size_t)(j * 64 + lane) * 4;
        __builtin_amdgcn_global_load_lds(
            (glb_void_t*)g,
            (lds_void_t*)&tile[wave][j * 256],
            16, 0, 0);
    }
    __builtin_amdgcn_s_waitcnt(0x0f70);  // vmcnt(0)

    // ---- lane r of node nloc owns k = 4r..4r+3 as two vertical v2f chains ----
    // chainA = {k=4r, 4r+1}, chainB = {4r+2, 4r+3}; pair elements are 7 LDS
    // dwords apart -> ds_read2_b32 (offsets j, j+7 / 14+j, 21+j from lane base).
    const int nloc = lane >> 2;
    const int r = lane & 3;
    const int base = nloc * NODE_FLOATS + r * 28;
    v2f mA[F_IN], mB[F_IN];
    #pragma unroll
    for (int j = 0; j < F_IN; ++j) {
        v2f a, b;
        a.x = tile[wave][base + j];
        a.y = tile[wave][base + 7 + j];
        b.x = tile[wave][base + 14 + j];
        b.y = tile[wave][base + 21 + j];
        mA[j] = a;
        mB[j] = b;
    }

    // Weights via constant address space: wave-uniform address -> s_load (SMEM
    // pipe, K$), zero LDS/VMEM cost in the hot loop.
    const kfloat* wt  = (const kfloat*)(uintptr_t)wtab;
    const kfloat* w2t = (const kfloat*)(uintptr_t)w2tab;

    const v2f zero = {0.0f, 0.0f};
    v2f a0 = zero, a1 = zero, a2 = zero;

    #pragma unroll 4
    for (int h = 0; h < F_HID; ++h) {
        const float w0 = wt[h * 8 + 0];
        const float w1 = wt[h * 8 + 1];
        const float w2 = wt[h * 8 + 2];
        const float w3 = wt[h * 8 + 3];
        const float w4 = wt[h * 8 + 4];
        const float w5 = wt[h * 8 + 5];
        const float w6 = wt[h * 8 + 6];
        const float bb = wt[h * 8 + 7];

        const v2f wv0 = {w0, w0}, wv1 = {w1, w1}, wv2 = {w2, w2};
        const v2f wv3 = {w3, w3}, wv4 = {w4, w4}, wv5 = {w5, w5};
        const v2f wv6 = {w6, w6}, bbv = {bb, bb};

        v2f accA = mA[0] * wv0;
        v2f accB = mB[0] * wv0;
        accA = __builtin_elementwise_fma(mA[1], wv1, accA);
        accB = __builtin_elementwise_fma(mB[1], wv1, accB);
        accA = __builtin_elementwise_fma(mA[2], wv2, accA);
        accB = __builtin_elementwise_fma(mB[2], wv2, accB);
        accA = __builtin_elementwise_fma(mA[3], wv3, accA);
        accB = __builtin_elementwise_fma(mB[3], wv3, accB);
        accA = __builtin_elementwise_fma(mA[4], wv4, accA);
        accB = __builtin_elementwise_fma(mB[4], wv4, accB);
        accA = __builtin_elementwise_fma(mA[5], wv5, accA);
        accB = __builtin_elementwise_fma(mB[5], wv5, accB);
        accA = __builtin_elementwise_fma(mA[6], wv6, accA);
        accB = __builtin_elementwise_fma(mB[6], wv6, accB);

        accA = __builtin_elementwise_max(accA + bbv, zero);   // relu(. + b1)
        accB = __builtin_elementwise_max(accB + bbv, zero);
        const v2f sh = accA + accB;   // {k:4r + 4r+2, 4r+1 + 4r+3} partials

        const float u0 = w2t[h * 4 + 0];
        const float u1 = w2t[h * 4 + 1];
        const float u2 = w2t[h * 4 + 2];
        const v2f uv0 = {u0, u0}, uv1 = {u1, u1}, uv2 = {u2, u2};
        a0 = __builtin_elementwise_fma(sh, uv0, a0);
        a1 = __builtin_elementwise_fma(sh, uv1, a1);
        a2 = __builtin_elementwise_fma(sh, uv2, a2);
    }

    // ---- horizontal: packed halves, then quad-reduce over the 4 lanes ----
    float s0 = a0.x + a0.y;
    float s1 = a1.x + a1.y;
    float s2 = a2.x + a2.y;
    s0 += __shfl_xor(s0, 1); s0 += __shfl_xor(s0, 2);
    s1 += __shfl_xor(s1, 1); s1 += __shfl_xor(s1, 2);
    s2 += __shfl_xor(s2, 1); s2 += __shfl_xor(s2, 2);

    if (r < F_OUT) {
        const float val = (r == 0) ? s0 : ((r == 1) ? s1 : s2);
        out[(size_t)(tile0 + nloc) * F_OUT + r] =
            fmaf(val, 1.0f / (float)K_NB, b2[r]);
    }
}

extern "C" void kernel_launch(void* const* d_in, const int* in_sizes, int n_in,
                              void* d_out, int out_size, void* d_ws, size_t ws_size,
                              hipStream_t stream) {
    const float* mailbox = (const float*)d_in[0];
    const float* W1      = (const float*)d_in[1];
    const float* b1      = (const float*)d_in[2];
    const float* W2      = (const float*)d_in[3];
    const float* b2      = (const float*)d_in[4];
    float* ws  = (float*)d_ws;
    float* out = (float*)d_out;

    prep_kernel<<<1, 128, 0, stream>>>(W1, b1, W2, ws);

    const float* wtab  = ws;             // 40*8 floats
    const float* w2tab = ws + F_HID * 8; // 40*4 floats
    aggre_kernel<<<NBLK, 256, 0, stream>>>(mailbox, wtab, w2tab, b2, out);
}